// Round 5
// baseline (147.836 us; speedup 1.0000x reference)
//
#include <hip/hip_runtime.h>

// B=8, N=2048, D=32, H=4, HD=8, BH=32
// ws layout:
//   q16  [32][2048][8]  f16  (1MB)
//   k16  [32][2048][8]  f16  (1MB)
//   vT16 [32][16][2048] f16  (2MB)  rows 0..7 = V^T, row 8 = ones, 9..15 = 0
//   attn_ws [8][2048][32] f32 (2MB)
//
// R4/R5: MFMA attention. Swapped QK^T (mfma(K,Q) -> S^T) makes the 16x16x16
// C-layout (q=lane&15, j=(lane>>4)*4+reg) identical to the PV A-operand
// layout -> zero cross-lane fixup. Ones-row in V^T gives the softmax
// denominator from the same PV MFMA.

typedef _Float16 f16;
typedef _Float16 f16x2 __attribute__((ext_vector_type(2)));
typedef _Float16 f16x4 __attribute__((ext_vector_type(4)));
typedef __fp16 h16x2 __attribute__((ext_vector_type(2)));  // cvt_pkrtz result type
typedef float f32x4 __attribute__((ext_vector_type(4)));

__global__ __launch_bounds__(256) void qkv_kernel(
    const float* __restrict__ x, const float* __restrict__ Wqkv,
    const float* __restrict__ bqkv, f16* __restrict__ q16,
    f16* __restrict__ k16, f16* __restrict__ vT16) {
  __shared__ float Ws[32 * 96];
  __shared__ float bsh[96];
  __shared__ float xs[16 * 32];
  int tid = threadIdx.x;
  for (int i = tid; i < 32 * 96; i += 256) Ws[i] = Wqkv[i];
  if (tid < 96) bsh[tid] = bqkv[tid];
  int rowbase = blockIdx.x * 16;
  for (int i = tid; i < 16 * 32; i += 256) xs[i] = x[rowbase * 32 + i];
  __syncthreads();
#pragma unroll
  for (int e = 0; e < 6; ++e) {
    int idx = tid + e * 256;
    int r = idx / 96, c = idx % 96;
    float acc = bsh[c];
#pragma unroll
    for (int k = 0; k < 32; ++k) acc += xs[r * 32 + k] * Ws[k * 96 + c];
    int nrow = rowbase + r;
    int b = nrow >> 11, n = nrow & 2047;
    int s = c >> 5, h = (c >> 3) & 3, d = c & 7;
    int bh = b * 4 + h;
    if (s == 0)      q16[((size_t)bh * 2048 + n) * 8 + d] = (f16)acc;
    else if (s == 1) k16[((size_t)bh * 2048 + n) * 8 + d] = (f16)acc;
    else             vT16[((size_t)bh * 16 + d) * 2048 + n] = (f16)acc;
  }
  // fill vT16 rows 8..15 every launch (row 8 = ones for the denom trick).
  // 32 bh * 8 rows * 2048 = 524288 f16 = 262144 f16x2; grid 1024*256 exact.
  int f = (blockIdx.x * 256 + tid) * 2;
  int bh = f >> 14, rem = f & 16383;
  int row = rem >> 11, j = rem & 2047;
  f16 one = (f16)((row == 0) ? 1.f : 0.f);
  f16x2 val = {one, one};
  *(f16x2*)(vT16 + ((size_t)bh * 16 + 8 + row) * 2048 + j) = val;
}

__global__ __launch_bounds__(256) void attn_kernel(
    const f16* __restrict__ q16, const f16* __restrict__ k16,
    const f16* __restrict__ vT16, const float* __restrict__ adj,
    const float* __restrict__ gw_p, float* __restrict__ attn_ws) {
  int blk = blockIdx.x;
  int bh = blk & 31, qg = blk >> 5;     // bh fastest: 32 blocks share adj rows
  int wave = threadIdx.x >> 6, lane = threadIdx.x & 63;
  int b = bh >> 2, h = bh & 3;
  int qt0 = qg * 64 + wave * 16;        // this wave's 16-query tile
  int lq = lane & 15, lh = lane >> 4;   // lq: q (and V d-col); lh: 4-slice idx

  const float LOG2E = 1.4426950408889634f;
  float gw = gw_p[0];
  float blend = 1.f / (1.f + __expf(-gw));
  float c1 = (1.f - blend) * 0.35355339059327373f * LOG2E;
  float c2 = blend * 5.f * LOG2E;

  const f16* qb = q16 + (size_t)bh * 2048 * 8;
  const f16* kp = k16 + (size_t)bh * 2048 * 8 + lq * 8 + lh * 4;
  const f16* vp = vT16 + (size_t)bh * 16 * 2048 + lq * 2048 + lh * 4;
  const float* ap = adj + (size_t)(qt0 + lq) * 2048 + lh * 4;

  // B operand (Q): lane holds Q[q=lq][d=lh*4+e]; d>=8 lanes are zero.
  f16x4 qf = {};
  if (lane < 32) qf = *(const f16x4*)(qb + (qt0 + lq) * 8 + lh * 4);

  f32x4 acc = {0.f, 0.f, 0.f, 0.f};
  const f32x4 zero4 = {0.f, 0.f, 0.f, 0.f};

  for (int jt = 0; jt < 128; ++jt) {
    // A operand (K): lane holds K[j=lq][d=lh*4+e]; d>=8 lanes zero.
    f16x4 kf = {};
    if (lane < 32) kf = *(const f16x4*)(kp + jt * 128);
    // B operand (V^T): lane holds V[j=lh*4+e][d=lq] (row 8 = ones)
    f16x4 vf = *(const f16x4*)(vp + jt * 16);
    // adj gather: lane/reg r -> adj[q=qt0+lq][j=jt*16+lh*4+r], float4 coalesced
    f32x4 av = *(const f32x4*)(ap + jt * 16);

    // S^T tile: s[r] = dot(K[j=lh*4+r], Q[q=lq])
    f32x4 s = __builtin_amdgcn_mfma_f32_16x16x16f16(kf, qf, zero4, 0, 0, 0);
    float e0 = __builtin_amdgcn_exp2f(fmaf(c1, s[0], c2 * av[0]));
    float e1 = __builtin_amdgcn_exp2f(fmaf(c1, s[1], c2 * av[1]));
    float e2 = __builtin_amdgcn_exp2f(fmaf(c1, s[2], c2 * av[2]));
    float e3 = __builtin_amdgcn_exp2f(fmaf(c1, s[3], c2 * av[3]));
    h16x2 h01 = __builtin_amdgcn_cvt_pkrtz(e0, e1);
    h16x2 h23 = __builtin_amdgcn_cvt_pkrtz(e2, e3);
    // half->float->half is exact identity; LLVM folds to a plain move.
    f16x4 pa;
    pa[0] = (f16)(float)h01[0];
    pa[1] = (f16)(float)h01[1];
    pa[2] = (f16)(float)h23[0];
    pa[3] = (f16)(float)h23[1];  // P[q=lq][j=lh*4+e]
    // out[q][d] += P[q][j] * V[j][d]; col d=8 accumulates sum(p)
    acc = __builtin_amdgcn_mfma_f32_16x16x16f16(pa, vf, acc, 0, 0, 0);
  }

  // acc(l,r) = out[q=lh*4+r][d=lq]; denominator lives at lane (lh*16)|8
  int dsrc = (lane & 48) | 8;
  float den0 = __shfl(acc[0], dsrc);
  float den1 = __shfl(acc[1], dsrc);
  float den2 = __shfl(acc[2], dsrc);
  float den3 = __shfl(acc[3], dsrc);
  if (lq < 8) {
    size_t base = ((size_t)b * 2048 + qt0 + lh * 4) * 32 + h * 8 + lq;
    attn_ws[base]      = acc[0] / den0;
    attn_ws[base + 32] = acc[1] / den1;
    attn_ws[base + 64] = acc[2] / den2;
    attn_ws[base + 96] = acc[3] / den3;
  }
}

__global__ __launch_bounds__(256) void out_ln_kernel(
    const float* __restrict__ attn_ws, const float* __restrict__ x,
    const float* __restrict__ Wout, const float* __restrict__ bout,
    const float* __restrict__ gamma, const float* __restrict__ beta,
    float* __restrict__ out) {
  __shared__ float Ws[32 * 32];
  __shared__ float bs[32], gs[32], bts[32];
  int tid = threadIdx.x;
  for (int i = tid; i < 1024; i += 256) Ws[i] = Wout[i];
  if (tid < 32) { bs[tid] = bout[tid]; gs[tid] = gamma[tid]; bts[tid] = beta[tid]; }
  __syncthreads();
  int row = blockIdx.x * 8 + (tid >> 5);
  int d = tid & 31;
  const float* ar = attn_ws + (size_t)row * 32;
  float acc = bs[d];
#pragma unroll
  for (int k = 0; k < 32; ++k) acc += ar[k] * Ws[k * 32 + d];
  float res = acc + x[(size_t)row * 32 + d];
  float s1 = res, s2 = res * res;
#pragma unroll
  for (int off = 16; off >= 1; off >>= 1) {
    s1 += __shfl_xor(s1, off);
    s2 += __shfl_xor(s2, off);
  }
  float mu = s1 * 0.03125f;
  float var = s2 * 0.03125f - mu * mu;
  float r = rsqrtf(var + 1e-5f);
  out[(size_t)row * 32 + d] = (res - mu) * r * gs[d] + bts[d];
}

extern "C" void kernel_launch(void* const* d_in, const int* in_sizes, int n_in,
                              void* d_out, int out_size, void* d_ws, size_t ws_size,
                              hipStream_t stream) {
  const float* x     = (const float*)d_in[0];
  const float* adj   = (const float*)d_in[1];
  const float* gw    = (const float*)d_in[2];
  const float* Wqkv  = (const float*)d_in[3];
  const float* bqkv  = (const float*)d_in[4];
  const float* Wout  = (const float*)d_in[5];
  const float* bout  = (const float*)d_in[6];
  const float* gamma = (const float*)d_in[7];
  const float* beta  = (const float*)d_in[8];
  float* out = (float*)d_out;

  char* wsb = (char*)d_ws;
  f16* q16      = (f16*)wsb;                    // 1MB
  f16* k16      = (f16*)(wsb + (1 << 20));      // 1MB
  f16* vT16     = (f16*)(wsb + (2 << 20));      // 2MB
  float* attn_ws = (float*)(wsb + (4 << 20));   // 2MB

  qkv_kernel<<<1024, 256, 0, stream>>>(x, Wqkv, bqkv, q16, k16, vT16);
  attn_kernel<<<1024, 256, 0, stream>>>(q16, k16, vT16, adj, gw, attn_ws);
  out_ln_kernel<<<2048, 256, 0, stream>>>(attn_ws, x, Wout, bout, gamma, beta, out);
}